// Round 1
// baseline (16177.832 us; speedup 1.0000x reference)
//
#include <hip/hip_runtime.h>
#include <math.h>

#define B_  64
#define T_  150
#define L_  256
#define H_  512
#define E_  512
#define V_  1000
#define G4_ 2048   // 4*H

__device__ __forceinline__ float sigmf(float x) { return 1.0f / (1.0f + expf(-x)); }

// ---------------- generic NT GEMM: C[M][N] = op(A[M][K]) @ B[N][K]^T + bias1 + bias2
template<bool RELU_A>
__global__ __launch_bounds__(256) void gemm_nt_bias(
    const float* __restrict__ A, const float* __restrict__ Bm,
    const float* __restrict__ bias1, const float* __restrict__ bias2,
    float* __restrict__ C, int M, int N, int K)
{
    __shared__ __align__(16) float As[16][68];
    __shared__ __align__(16) float Bs[16][68];
    const int tid = threadIdx.x;
    const int m0 = blockIdx.x * 64;
    const int n0 = blockIdx.y * 64;
    const int lr = tid >> 2;          // 0..63
    const int lc = (tid & 3) << 2;    // 0,4,8,12
    const int tm = (tid & 15) << 2;   // 0..60
    const int tn = (tid >> 4) << 2;   // 0..60
    float acc[4][4] = {};

    for (int kb = 0; kb < K; kb += 16) {
        float4 a4 = make_float4(0.f, 0.f, 0.f, 0.f);
        int gm = m0 + lr;
        if (gm < M) a4 = *(const float4*)(A + (size_t)gm * K + kb + lc);
        if (RELU_A) {
            a4.x = fmaxf(a4.x, 0.f); a4.y = fmaxf(a4.y, 0.f);
            a4.z = fmaxf(a4.z, 0.f); a4.w = fmaxf(a4.w, 0.f);
        }
        As[lc + 0][lr] = a4.x; As[lc + 1][lr] = a4.y;
        As[lc + 2][lr] = a4.z; As[lc + 3][lr] = a4.w;

        float4 b4 = make_float4(0.f, 0.f, 0.f, 0.f);
        int gn = n0 + lr;
        if (gn < N) b4 = *(const float4*)(Bm + (size_t)gn * K + kb + lc);
        Bs[lc + 0][lr] = b4.x; Bs[lc + 1][lr] = b4.y;
        Bs[lc + 2][lr] = b4.z; Bs[lc + 3][lr] = b4.w;
        __syncthreads();

        #pragma unroll
        for (int k = 0; k < 16; ++k) {
            float4 av = *(const float4*)&As[k][tm];
            float4 bv = *(const float4*)&Bs[k][tn];
            float af[4] = {av.x, av.y, av.z, av.w};
            float bf[4] = {bv.x, bv.y, bv.z, bv.w};
            #pragma unroll
            for (int i = 0; i < 4; ++i)
                #pragma unroll
                for (int j = 0; j < 4; ++j)
                    acc[i][j] += af[i] * bf[j];
        }
        __syncthreads();
    }

    #pragma unroll
    for (int i = 0; i < 4; ++i) {
        int gm = m0 + tm + i;
        if (gm >= M) continue;
        #pragma unroll
        for (int j = 0; j < 4; ++j) {
            int gn = n0 + tn + j;
            if (gn >= N) continue;
            float v = acc[i][j];
            if (bias1) v += bias1[gn];
            if (bias2) v += bias2[gn];
            C[(size_t)gm * N + gn] = v;
        }
    }
}

// ---------------- tiled transpose: out[C][R] = in[R][C]^T
__global__ __launch_bounds__(256) void transpose_k(
    const float* __restrict__ in, float* __restrict__ out, int R, int C)
{
    __shared__ float tile[32][33];
    int c0 = blockIdx.x * 32, r0 = blockIdx.y * 32;
    int x = threadIdx.x & 31, y = threadIdx.x >> 5;
    for (int i = y; i < 32; i += 8) {
        int r = r0 + i, cc = c0 + x;
        tile[i][x] = (r < R && cc < C) ? in[(size_t)r * C + cc] : 0.f;
    }
    __syncthreads();
    for (int i = y; i < 32; i += 8) {
        int cc = c0 + i, r = r0 + x;
        if (cc < C && r < R) out[(size_t)cc * R + r] = tile[x][i];
    }
}

// ---------------- the serial decoder: one block per batch element, loops all T steps
__global__ __launch_bounds__(1024) void decoder_loop(
    const float* __restrict__ cnn,   // [B][L][H]
    const int*   __restrict__ seq,   // [B][T]
    const float* __restrict__ G,     // [V][4H]  pregate table
    const float* __restrict__ WhhT,  // [H][4H]
    const float* __restrict__ WhmT,  // [H][H]
    const float* __restrict__ WomT,  // [2H][H]
    float* __restrict__ outbuf)      // [B*T][H]
{
    const int b    = blockIdx.x;
    const int tid  = threadIdx.x;
    const int lane = tid & 63;
    const int wave = tid >> 6;   // 16 waves

    __shared__ __align__(16) float h[H_];
    __shared__ __align__(16) float c[H_];
    __shared__ __align__(16) float gates[G4_];
    __shared__ __align__(16) float mapped[H_];
    __shared__ __align__(16) float part[1024];
    __shared__ __align__(16) float att[L_];
    __shared__ __align__(16) float ctx[H_];

    if (tid < H_) { h[tid] = 0.f; c[tid] = 0.f; }
    __syncthreads();

    const float* cnnb = cnn + (size_t)b * L_ * H_;

    for (int t = 0; t < T_; ++t) {
        const int v = seq[b * T_ + t];
        // ---- gates[j] = G[v][j] + sum_k WhhT[k][j] * h[k]   (thread -> j = 2*tid, 2*tid+1)
        {
            float2 acc = ((const float2*)(G + (size_t)v * G4_))[tid];
            const float2* W2 = (const float2*)WhhT + tid;
            #pragma unroll 8
            for (int k = 0; k < H_; ++k) {
                float hk = h[k];
                float2 w = W2[(size_t)k * (G4_ / 2)];
                acc.x += w.x * hk; acc.y += w.y * hk;
            }
            gates[2 * tid]     = acc.x;
            gates[2 * tid + 1] = acc.y;
        }
        __syncthreads();
        // ---- LSTM cell
        if (tid < H_) {
            float ig = sigmf(gates[tid]);
            float fg = sigmf(gates[H_ + tid]);
            float gg = tanhf(gates[2 * H_ + tid]);
            float og = sigmf(gates[3 * H_ + tid]);
            float c2 = fg * c[tid] + ig * gg;
            c[tid] = c2;
            h[tid] = og * tanhf(c2);
        }
        __syncthreads();
        // ---- mapped[j] = sum_k WhmT[k][j] * h[k]   (split k over two halves of the block)
        {
            int j = tid & (H_ - 1), half = tid >> 9;
            float a = 0.f;
            const float* Wp = WhmT + (size_t)(half * 256) * H_ + j;
            const float* hp = h + half * 256;
            #pragma unroll 8
            for (int k = 0; k < 256; ++k) a += Wp[(size_t)k * H_] * hp[k];
            part[tid] = a;
        }
        __syncthreads();
        if (tid < H_) mapped[tid] = part[tid] + part[tid + H_];
        __syncthreads();
        // ---- attention scores: att[l] = cnn[b][l][:] . mapped
        for (int l = wave; l < L_; l += 16) {
            const float4* row = (const float4*)(cnnb + (size_t)l * H_);
            const float4* mp  = (const float4*)mapped;
            float4 r0 = row[lane * 2],     m0 = mp[lane * 2];
            float4 r1 = row[lane * 2 + 1], m1 = mp[lane * 2 + 1];
            float s = r0.x * m0.x + r0.y * m0.y + r0.z * m0.z + r0.w * m0.w
                    + r1.x * m1.x + r1.y * m1.y + r1.z * m1.z + r1.w * m1.w;
            #pragma unroll
            for (int off = 32; off; off >>= 1) s += __shfl_xor(s, off);
            if (lane == 0) att[l] = s;
        }
        __syncthreads();
        // ---- softmax over 256 (wave 0)
        if (wave == 0) {
            float4 sc = ((const float4*)att)[lane];
            float mx = fmaxf(fmaxf(sc.x, sc.y), fmaxf(sc.z, sc.w));
            #pragma unroll
            for (int off = 32; off; off >>= 1) mx = fmaxf(mx, __shfl_xor(mx, off));
            float e0 = expf(sc.x - mx), e1 = expf(sc.y - mx);
            float e2 = expf(sc.z - mx), e3 = expf(sc.w - mx);
            float ssum = e0 + e1 + e2 + e3;
            #pragma unroll
            for (int off = 32; off; off >>= 1) ssum += __shfl_xor(ssum, off);
            float inv = 1.f / ssum;
            float4 w4 = make_float4(e0 * inv, e1 * inv, e2 * inv, e3 * inv);
            ((float4*)att)[lane] = w4;
        }
        __syncthreads();
        // ---- ctx[j] = sum_l att[l] * cnn[b][l][j]   (split l over halves)
        {
            int j = tid & (H_ - 1), half = tid >> 9;
            float a = 0.f;
            const float* cp = cnnb + (size_t)(half * 128) * H_ + j;
            const float* ap = att + half * 128;
            #pragma unroll 8
            for (int l = 0; l < 128; ++l) a += cp[(size_t)l * H_] * ap[l];
            part[tid] = a;
        }
        __syncthreads();
        if (tid < H_) ctx[tid] = part[tid] + part[tid + H_];
        __syncthreads();
        // ---- out[j] = sum_k WomT[k][j]*ctx[k] + sum_k WomT[512+k][j]*h[k]
        {
            int j = tid & (H_ - 1), half = tid >> 9;
            const float* src = half ? h : ctx;
            const float* Wp = WomT + (size_t)(half * H_) * H_ + j;
            float a = 0.f;
            #pragma unroll 8
            for (int k = 0; k < H_; ++k) a += Wp[(size_t)k * H_] * src[k];
            part[tid] = a;
        }
        __syncthreads();
        if (tid < H_) outbuf[((size_t)b * T_ + t) * H_ + tid] = part[tid] + part[tid + H_];
        __syncthreads();
    }
}

// ---------------- per-row log_softmax over V=1000, in place
__global__ __launch_bounds__(256) void logsoftmax_k(float* __restrict__ out)
{
    const int row = blockIdx.x;
    float* p = out + (size_t)row * V_;
    const int tid = threadIdx.x, lane = tid & 63, wave = tid >> 6;
    __shared__ float red[8];

    float vals[4];
    int n = 0;
    float mx = -INFINITY;
    for (int v = tid; v < V_; v += 256) { vals[n] = p[v]; mx = fmaxf(mx, vals[n]); ++n; }
    #pragma unroll
    for (int off = 32; off; off >>= 1) mx = fmaxf(mx, __shfl_xor(mx, off));
    if (lane == 0) red[wave] = mx;
    __syncthreads();
    mx = fmaxf(fmaxf(red[0], red[1]), fmaxf(red[2], red[3]));

    float s = 0.f;
    for (int i = 0; i < n; ++i) s += expf(vals[i] - mx);
    #pragma unroll
    for (int off = 32; off; off >>= 1) s += __shfl_xor(s, off);
    if (lane == 0) red[4 + wave] = s;
    __syncthreads();
    s = red[4] + red[5] + red[6] + red[7];

    const float lse = mx + logf(s);
    n = 0;
    for (int v = tid; v < V_; v += 256) { p[v] = vals[n] - lse; ++n; }
}

extern "C" void kernel_launch(void* const* d_in, const int* in_sizes, int n_in,
                              void* d_out, int out_size, void* d_ws, size_t ws_size,
                              hipStream_t stream)
{
    const float* cnn     = (const float*)d_in[0];
    const int*   seq     = (const int*)d_in[1];
    const float* embed   = (const float*)d_in[2];
    const float* W_ih    = (const float*)d_in[3];
    const float* b_ih    = (const float*)d_in[4];
    const float* W_hh    = (const float*)d_in[5];
    const float* b_hh    = (const float*)d_in[6];
    const float* W_hm    = (const float*)d_in[7];
    const float* W_om    = (const float*)d_in[8];
    const float* W_logit = (const float*)d_in[9];
    const float* b_logit = (const float*)d_in[10];
    float* out = (float*)d_out;

    float* ws = (float*)d_ws;
    float* G      = ws;                               // V_*G4_     = 2,048,000
    float* WhhT   = G + (size_t)V_ * G4_;             // H_*G4_     = 1,048,576
    float* WhmT   = WhhT + (size_t)H_ * G4_;          // H_*H_      =   262,144
    float* WomT   = WhmT + (size_t)H_ * H_;           // 2H*H       =   524,288
    float* outbuf = WomT + (size_t)2 * H_ * H_;       // B_*T_*H_   = 4,915,200

    // pregate table: G[v][:] = relu(embed[v]) @ W_ih^T + b_ih + b_hh
    {
        dim3 g((V_ + 63) / 64, G4_ / 64);
        gemm_nt_bias<true><<<g, 256, 0, stream>>>(embed, W_ih, b_ih, b_hh, G, V_, G4_, E_);
    }
    // weight transposes (coalesced per-step matvec reads)
    transpose_k<<<dim3(H_ / 32, G4_ / 32), 256, 0, stream>>>(W_hh, WhhT, G4_, H_);
    transpose_k<<<dim3(H_ / 32, H_ / 32), 256, 0, stream>>>(W_hm, WhmT, H_, H_);
    transpose_k<<<dim3(2 * H_ / 32, H_ / 32), 256, 0, stream>>>(W_om, WomT, H_, 2 * H_);

    // serial recurrence: one block per batch element
    decoder_loop<<<B_, 1024, 0, stream>>>(cnn, seq, G, WhhT, WhmT, WomT, outbuf);

    // logits GEMM + log_softmax
    {
        dim3 g((B_ * T_) / 64, (V_ + 63) / 64);
        gemm_nt_bias<false><<<g, 256, 0, stream>>>(outbuf, W_logit, b_logit, nullptr, out,
                                                   B_ * T_, V_, H_);
    }
    logsoftmax_k<<<B_ * T_, 256, 0, stream>>>(out);
}

// Round 2
// 5244.185 us; speedup vs baseline: 3.0849x; 3.0849x over previous
//
#include <hip/hip_runtime.h>
#include <math.h>

#define B_  64
#define T_  150
#define L_  256
#define H_  512
#define E_  512
#define V_  1000
#define G4_ 2048   // 4*H

__device__ __forceinline__ float sigmf(float x) { return 1.0f / (1.0f + expf(-x)); }

// ---------------- generic NT GEMM: C[M][N] = op(A[M][K]) @ B[N][K]^T (+bias)(+accum)
// z-strides allow per-batch GEMMs. REMAP: output row gm=(t*64+b) -> (b*150+t).
template<bool RELU_A, bool ACCUM, bool REMAP>
__global__ __launch_bounds__(256) void gemm_nt(
    const float* __restrict__ A, size_t lda, size_t azs,
    const float* __restrict__ Bm, size_t ldb, size_t bzs,
    const float* __restrict__ bias1, const float* __restrict__ bias2,
    float* __restrict__ C, size_t ldc, size_t czs, int M, int N, int K)
{
    A  += blockIdx.z * azs;
    Bm += blockIdx.z * bzs;
    C  += blockIdx.z * czs;
    __shared__ __align__(16) float As[16][68];
    __shared__ __align__(16) float Bs[16][68];
    const int tid = threadIdx.x;
    const int m0 = blockIdx.x * 64;
    const int n0 = blockIdx.y * 64;
    const int lr = tid >> 2;          // 0..63
    const int lc = (tid & 3) << 2;    // 0,4,8,12
    const int tm = (tid & 15) << 2;   // 0..60
    const int tn = (tid >> 4) << 2;   // 0..60
    float acc[4][4] = {};

    for (int kb = 0; kb < K; kb += 16) {
        float4 a4 = make_float4(0.f, 0.f, 0.f, 0.f);
        int gm = m0 + lr;
        if (gm < M) a4 = *(const float4*)(A + (size_t)gm * lda + kb + lc);
        if (RELU_A) {
            a4.x = fmaxf(a4.x, 0.f); a4.y = fmaxf(a4.y, 0.f);
            a4.z = fmaxf(a4.z, 0.f); a4.w = fmaxf(a4.w, 0.f);
        }
        As[lc + 0][lr] = a4.x; As[lc + 1][lr] = a4.y;
        As[lc + 2][lr] = a4.z; As[lc + 3][lr] = a4.w;

        float4 b4 = make_float4(0.f, 0.f, 0.f, 0.f);
        int gn = n0 + lr;
        if (gn < N) b4 = *(const float4*)(Bm + (size_t)gn * ldb + kb + lc);
        Bs[lc + 0][lr] = b4.x; Bs[lc + 1][lr] = b4.y;
        Bs[lc + 2][lr] = b4.z; Bs[lc + 3][lr] = b4.w;
        __syncthreads();

        #pragma unroll
        for (int k = 0; k < 16; ++k) {
            float4 av = *(const float4*)&As[k][tm];
            float4 bv = *(const float4*)&Bs[k][tn];
            float af[4] = {av.x, av.y, av.z, av.w};
            float bf[4] = {bv.x, bv.y, bv.z, bv.w};
            #pragma unroll
            for (int i = 0; i < 4; ++i)
                #pragma unroll
                for (int j = 0; j < 4; ++j)
                    acc[i][j] += af[i] * bf[j];
        }
        __syncthreads();
    }

    #pragma unroll
    for (int i = 0; i < 4; ++i) {
        int gm = m0 + tm + i;
        if (gm >= M) continue;
        size_t row = REMAP ? ((size_t)(gm & 63) * T_ + (gm >> 6)) : (size_t)gm;
        #pragma unroll
        for (int j = 0; j < 4; ++j) {
            int gn = n0 + tn + j;
            if (gn >= N) continue;
            float v = acc[i][j];
            if (bias1) v += bias1[gn];
            if (bias2) v += bias2[gn];
            if (ACCUM) v += C[row * ldc + gn];
            C[row * ldc + gn] = v;
        }
    }
}

// ---------------- NN GEMM: C[M][N] = A[M][K] @ B[K][N]  (for ctx = att @ cnn)
__global__ __launch_bounds__(256) void gemm_nn(
    const float* __restrict__ A, size_t lda, size_t azs,
    const float* __restrict__ Bm, size_t ldb, size_t bzs,
    float* __restrict__ C, size_t ldc, size_t czs, int M, int N, int K)
{
    A  += blockIdx.z * azs;
    Bm += blockIdx.z * bzs;
    C  += blockIdx.z * czs;
    __shared__ __align__(16) float As[16][68];
    __shared__ __align__(16) float Bs[16][68];
    const int tid = threadIdx.x;
    const int m0 = blockIdx.x * 64;
    const int n0 = blockIdx.y * 64;
    const int lr = tid >> 2;          // 0..63
    const int lc = (tid & 3) << 2;    // 0,4,8,12
    const int br = tid >> 4;          // 0..15
    const int bc = (tid & 15) << 2;   // 0..60
    const int tm = (tid & 15) << 2;
    const int tn = (tid >> 4) << 2;
    float acc[4][4] = {};

    for (int kb = 0; kb < K; kb += 16) {
        float4 a4 = make_float4(0.f, 0.f, 0.f, 0.f);
        int gm = m0 + lr;
        if (gm < M) a4 = *(const float4*)(A + (size_t)gm * lda + kb + lc);
        As[lc + 0][lr] = a4.x; As[lc + 1][lr] = a4.y;
        As[lc + 2][lr] = a4.z; As[lc + 3][lr] = a4.w;

        float4 b4 = make_float4(0.f, 0.f, 0.f, 0.f);
        if (n0 + bc < N) b4 = *(const float4*)(Bm + (size_t)(kb + br) * ldb + n0 + bc);
        Bs[br][bc + 0] = b4.x; Bs[br][bc + 1] = b4.y;
        Bs[br][bc + 2] = b4.z; Bs[br][bc + 3] = b4.w;
        __syncthreads();

        #pragma unroll
        for (int k = 0; k < 16; ++k) {
            float4 av = *(const float4*)&As[k][tm];
            float4 bv = *(const float4*)&Bs[k][tn];
            float af[4] = {av.x, av.y, av.z, av.w};
            float bf[4] = {bv.x, bv.y, bv.z, bv.w};
            #pragma unroll
            for (int i = 0; i < 4; ++i)
                #pragma unroll
                for (int j = 0; j < 4; ++j)
                    acc[i][j] += af[i] * bf[j];
        }
        __syncthreads();
    }

    #pragma unroll
    for (int i = 0; i < 4; ++i) {
        int gm = m0 + tm + i;
        if (gm >= M) continue;
        #pragma unroll
        for (int j = 0; j < 4; ++j) {
            int gn = n0 + tn + j;
            if (gn >= N) continue;
            C[(size_t)gm * ldc + gn] = acc[i][j];
        }
    }
}

// ---------------- tiled transpose: out[C][R] = in[R][C]^T
__global__ __launch_bounds__(256) void transpose_k(
    const float* __restrict__ in, float* __restrict__ out, int R, int C)
{
    __shared__ float tile[32][33];
    int c0 = blockIdx.x * 32, r0 = blockIdx.y * 32;
    int x = threadIdx.x & 31, y = threadIdx.x >> 5;
    for (int i = y; i < 32; i += 8) {
        int r = r0 + i, cc = c0 + x;
        tile[i][x] = (r < R && cc < C) ? in[(size_t)r * C + cc] : 0.f;
    }
    __syncthreads();
    for (int i = y; i < 32; i += 8) {
        int cc = c0 + i, r = r0 + x;
        if (cc < C && r < R) out[(size_t)cc * R + r] = tile[x][i];
    }
}

// ---------------- one LSTM time step, batched over all 64 b.
// Grid 128 blocks; block owns h-cols j0..j0+3 (gate cols in all 4 sections).
__global__ __launch_bounds__(256) void lstm_step(
    const float* __restrict__ hT_in,   // [H][B]
    float* __restrict__ hT_out,        // [H][B]
    float* __restrict__ cT,            // [H][B]
    const float* __restrict__ G,       // [V][4H]
    const float* __restrict__ WhhT,    // [H][4H]
    const int* __restrict__ seq,       // [B][T]
    float* __restrict__ hbuf_t,        // [B][H] slice at step t
    int t)
{
    __shared__ float gbuf[4 * 64 * 4];     // [q][b][m]
    const int tid = threadIdx.x;
    const int b   = tid & 63;
    const int q   = tid >> 6;              // gate section 0..3
    const int j0  = blockIdx.x * 4;
    const int col = q * H_ + j0;

    const int v = seq[b * T_ + t];
    float4 acc = *(const float4*)(G + (size_t)v * G4_ + col);

    const float* wp = WhhT + col;
    #pragma unroll 8
    for (int k = 0; k < H_; ++k) {
        float hk = hT_in[k * 64 + b];
        float4 w = *(const float4*)(wp + (size_t)k * G4_);
        acc.x += hk * w.x; acc.y += hk * w.y;
        acc.z += hk * w.z; acc.w += hk * w.w;
    }
    ((float4*)gbuf)[q * 64 + b] = acc;
    __syncthreads();

    // thread (b, m=q) finishes column j0+m
    const int m = q;
    float ig = gbuf[(0 * 64 + b) * 4 + m];
    float fg = gbuf[(1 * 64 + b) * 4 + m];
    float gg = gbuf[(2 * 64 + b) * 4 + m];
    float og = gbuf[(3 * 64 + b) * 4 + m];
    float cold = cT[(j0 + m) * 64 + b];
    float c2 = sigmf(fg) * cold + sigmf(ig) * tanhf(gg);
    float h2 = sigmf(og) * tanhf(c2);
    cT[(j0 + m) * 64 + b]     = c2;
    hT_out[(j0 + m) * 64 + b] = h2;
    hbuf_t[b * H_ + j0 + m]   = h2;
}

// ---------------- softmax over rows of 256 (attention weights), 4 rows/block
__global__ __launch_bounds__(256) void att_softmax(float* __restrict__ att, int nrows)
{
    const int tid = threadIdx.x, lane = tid & 63, wave = tid >> 6;
    const int row = blockIdx.x * 4 + wave;
    if (row >= nrows) return;
    float4* p = (float4*)(att + (size_t)row * L_);
    float4 sc = p[lane];
    float mx = fmaxf(fmaxf(sc.x, sc.y), fmaxf(sc.z, sc.w));
    #pragma unroll
    for (int off = 32; off; off >>= 1) mx = fmaxf(mx, __shfl_xor(mx, off));
    float e0 = expf(sc.x - mx), e1 = expf(sc.y - mx);
    float e2 = expf(sc.z - mx), e3 = expf(sc.w - mx);
    float s = e0 + e1 + e2 + e3;
    #pragma unroll
    for (int off = 32; off; off >>= 1) s += __shfl_xor(s, off);
    float inv = 1.f / s;
    p[lane] = make_float4(e0 * inv, e1 * inv, e2 * inv, e3 * inv);
}

// ---------------- per-row log_softmax over V=1000, in place
__global__ __launch_bounds__(256) void logsoftmax_k(float* __restrict__ out)
{
    const int row = blockIdx.x;
    float* p = out + (size_t)row * V_;
    const int tid = threadIdx.x, lane = tid & 63, wave = tid >> 6;
    __shared__ float red[8];

    float vals[4];
    int n = 0;
    float mx = -INFINITY;
    for (int v = tid; v < V_; v += 256) { vals[n] = p[v]; mx = fmaxf(mx, vals[n]); ++n; }
    #pragma unroll
    for (int off = 32; off; off >>= 1) mx = fmaxf(mx, __shfl_xor(mx, off));
    if (lane == 0) red[wave] = mx;
    __syncthreads();
    mx = fmaxf(fmaxf(red[0], red[1]), fmaxf(red[2], red[3]));

    float s = 0.f;
    for (int i = 0; i < n; ++i) s += expf(vals[i] - mx);
    #pragma unroll
    for (int off = 32; off; off >>= 1) s += __shfl_xor(s, off);
    if (lane == 0) red[4 + wave] = s;
    __syncthreads();
    s = red[4] + red[5] + red[6] + red[7];

    const float lse = mx + logf(s);
    n = 0;
    for (int v = tid; v < V_; v += 256) { p[v] = vals[n] - lse; ++n; }
}

extern "C" void kernel_launch(void* const* d_in, const int* in_sizes, int n_in,
                              void* d_out, int out_size, void* d_ws, size_t ws_size,
                              hipStream_t stream)
{
    const float* cnn     = (const float*)d_in[0];
    const int*   seq     = (const int*)d_in[1];
    const float* embed   = (const float*)d_in[2];
    const float* W_ih    = (const float*)d_in[3];
    const float* b_ih    = (const float*)d_in[4];
    const float* W_hh    = (const float*)d_in[5];
    const float* b_hh    = (const float*)d_in[6];
    const float* W_hm    = (const float*)d_in[7];
    const float* W_om    = (const float*)d_in[8];
    const float* W_logit = (const float*)d_in[9];
    const float* b_logit = (const float*)d_in[10];
    float* out = (float*)d_out;

    float* ws = (float*)d_ws;
    float* WhhT = ws;                                  // 512*2048   = 1,048,576
    float* G    = WhhT + (size_t)H_ * G4_;             // 1000*2048  = 2,048,000
    float* hT_a = G + (size_t)V_ * G4_;                // 512*64     =    32,768
    float* hT_b = hT_a + (size_t)H_ * B_;              //            =    32,768
    float* cT   = hT_b + (size_t)H_ * B_;              //            =    32,768
    float* hbuf = cT + (size_t)H_ * B_;                // 9600*512   = 4,915,200 (rows (t,b))
    float* outv = hbuf + (size_t)B_ * T_ * H_;         // 9600*512   = 4,915,200
    // scratch inside d_out (dead before final logits write):
    float* mapped = out;                               // 9600*512 (rows (t,b)); later reused as ctx
    float* attb   = out + (size_t)B_ * T_ * H_;        // 64*150*256 = 2,457,600

    // pregate table: G[v][:] = relu(embed[v]) @ W_ih^T + b_ih + b_hh
    gemm_nt<true, false, false><<<dim3(16, 32, 1), 256, 0, stream>>>(
        embed, E_, 0, W_ih, E_, 0, b_ih, b_hh, G, G4_, 0, V_, G4_, E_);
    // WhhT = W_hh^T  ([2048][512] -> [512][2048])
    transpose_k<<<dim3(H_ / 32, G4_ / 32), 256, 0, stream>>>(W_hh, WhhT, G4_, H_);
    // h0 = c0 = 0
    hipMemsetAsync(hT_a, 0, (size_t)H_ * B_ * sizeof(float), stream);
    hipMemsetAsync(cT,   0, (size_t)H_ * B_ * sizeof(float), stream);

    // ---- Phase 1: serial LSTM recurrence (only h,c carried) ----
    float* cur = hT_a;
    float* nxt = hT_b;
    for (int t = 0; t < T_; ++t) {
        lstm_step<<<128, 256, 0, stream>>>(cur, nxt, cT, G, WhhT, seq,
                                           hbuf + (size_t)t * B_ * H_, t);
        float* tmp = cur; cur = nxt; nxt = tmp;
    }

    // ---- Phase 2: everything else, batched over all 9600 (t,b) rows ----
    // mapped = h @ W_hm^T
    gemm_nt<false, false, false><<<dim3(150, 8, 1), 256, 0, stream>>>(
        hbuf, H_, 0, W_hm, H_, 0, nullptr, nullptr, mapped, H_, 0, B_ * T_, H_, H_);
    // att[b][t][l] = mapped[(t,b)] . cnn[b][l]
    gemm_nt<false, false, false><<<dim3(3, 4, 64), 256, 0, stream>>>(
        mapped, (size_t)B_ * H_, H_,            // A: row t stride B*H, z-offset b*H
        cnn, H_, (size_t)L_ * H_,               // B: cnn[b]
        nullptr, nullptr,
        attb, L_, (size_t)T_ * L_, T_, L_, H_);
    att_softmax<<<(B_ * T_ + 3) / 4, 256, 0, stream>>>(attb, B_ * T_);
    // ctx[(t,b)] = att[b][t] @ cnn[b]   (overwrites mapped)
    gemm_nn<<<dim3(3, 8, 64), 256, 0, stream>>>(
        attb, L_, (size_t)T_ * L_,
        cnn, H_, (size_t)L_ * H_,
        mapped, (size_t)B_ * H_, H_, T_, H_, L_);
    // out = ctx @ W_om[:, :512]^T + h @ W_om[:, 512:]^T
    gemm_nt<false, false, false><<<dim3(150, 8, 1), 256, 0, stream>>>(
        mapped, H_, 0, W_om, 2 * H_, 0, nullptr, nullptr, outv, H_, 0, B_ * T_, H_, H_);
    gemm_nt<false, true, false><<<dim3(150, 8, 1), 256, 0, stream>>>(
        hbuf, H_, 0, W_om + H_, 2 * H_, 0, nullptr, nullptr, outv, H_, 0, B_ * T_, H_, H_);
    // logits (+bias), remapping rows (t,b) -> (b,t) into d_out
    gemm_nt<false, false, true><<<dim3(150, 16, 1), 256, 0, stream>>>(
        outv, H_, 0, W_logit, H_, 0, b_logit, nullptr, out, V_, 0, B_ * T_, V_, H_);
    logsoftmax_k<<<B_ * T_, 256, 0, stream>>>(out);
}